// Round 4
// baseline (201.111 us; speedup 1.0000x reference)
//
#include <hip/hip_runtime.h>
#include <math.h>

#define B_ 2
#define S_ 2048
#define E_ 1024
#define H_ 16
#define DH_ 64
#define NE3_ 3072
#define MTOT_ (B_*S_)
#define QSCALE_ 0.18033688011112042f   // 0.125 * log2(e); P = exp2(s')

typedef __bf16 bf16;
typedef bf16 bf16x8 __attribute__((ext_vector_type(8)));
typedef bf16 bf16x4 __attribute__((ext_vector_type(4)));
typedef float f32x4 __attribute__((ext_vector_type(4)));

#define MFMA16(a,b,c) __builtin_amdgcn_mfma_f32_16x16x32_bf16(a,b,c,0,0,0)

// XOR swizzle: rows are 128B; slot = 16B unit.
#define F_(r) ((((r) & 7) ^ (((r) >> 3) & 7)))

__device__ inline void* lds_swz(void* base, int row, int bytecol) {
    return (char*)base + row * 128 + (bytecol ^ (F_(row) << 4));
}

__device__ inline unsigned cvt_pk_bf16(float lo, float hi) {
    unsigned r;
    asm("v_cvt_pk_bf16_f32 %0, %1, %2" : "=v"(r) : "v"(lo), "v"(hi));
    return r;
}

__device__ inline void gload_lds16(const void* g, void* l) {
    __builtin_amdgcn_global_load_lds(
        (const __attribute__((address_space(1))) void*)g,
        (__attribute__((address_space(3))) void*)l, 16, 0, 0);
}

// ---------------- fp32 -> bf16 convert, all three arrays in one launch --------
#define NX_ (MTOT_*E_)
#define NW_ (NE3_*E_)
#define NWO_ (E_*E_)
__global__ void k_f2b3(const float* __restrict__ x, const float* __restrict__ wq,
                       const float* __restrict__ wo,
                       bf16* __restrict__ xb, bf16* __restrict__ wqb,
                       bf16* __restrict__ wob) {
    const int i = blockIdx.x * 256 + threadIdx.x;
    const int idx = i * 4;
    const float* src; bf16* dst; int off;
    if (idx < NX_)            { src = x;  dst = xb;  off = idx; }
    else if (idx < NX_ + NW_) { src = wq; dst = wqb; off = idx - NX_; }
    else                      { src = wo; dst = wob; off = idx - NX_ - NW_; }
    float4 f = *reinterpret_cast<const float4*>(src + off);
    bf16x4 o;
    o[0] = (bf16)f.x; o[1] = (bf16)f.y; o[2] = (bf16)f.z; o[3] = (bf16)f.w;
    *reinterpret_cast<bf16x4*>(dst + off) = o;
}

// ---------------- GEMM: C = A @ W^T (+bias), swapped orientation ----------------
// acc[i][j] = MFMA(W-frag, X-frag): out rows = n, cols = m.
// MODE 0: QKV epilogue -> Qb(*QSCALE)/Kb [B,H,S,64] packed 8B; V^T [B,H,64,S] scalar.
// MODE 1: out epilogue -> fp32 d_out, float4 stores.
template<int MODE>
__global__ __launch_bounds__(256) void k_gemm(
    const bf16* __restrict__ A, const bf16* __restrict__ W,
    const float* __restrict__ bias,
    bf16* __restrict__ Qb, bf16* __restrict__ Kb, bf16* __restrict__ Vt,
    float* __restrict__ out)
{
    __shared__ __align__(16) bf16 At[2][128*64];
    __shared__ __align__(16) bf16 Bt[2][128*64];
    const int tid = threadIdx.x, lane = tid & 63, w = tid >> 6;
    const int wr = w >> 1, wc = w & 1;
    // XCD-chunked remap: each XCD owns contiguous n-stripes
    const int g = blockIdx.x;
    const int nxw = (MODE == 0 ? 3 : 1);          // n-chunks per XCD
    const int xcd = g & 7, li = g >> 3;
    const int m0 = (li & 31) * 128;
    const int n0 = (xcd * nxw + (li >> 5)) * 128;

    f32x4 acc[4][4] = {};
    const int lrow = lane >> 3, lcol = (lane & 7) * 8;

    auto stage = [&](int k0, int buf) {
        for (int c4 = 0; c4 < 4; ++c4) {
            const int c = w * 4 + c4;
            const int row = c * 8 + lrow;
            const int colx = lcol ^ (F_(row) * 8);
            gload_lds16(A + (size_t)(m0 + row) * E_ + k0 + colx, &At[buf][c * 512]);
            gload_lds16(W + (size_t)(n0 + row) * E_ + k0 + colx, &Bt[buf][c * 512]);
        }
    };
    stage(0, 0);
    __syncthreads();

    int cur = 0;
    for (int kt = 0; kt < E_/64; ++kt) {
        if (kt + 1 < E_/64) stage((kt + 1) * 64, cur ^ 1);
        for (int ks = 0; ks < 2; ++ks) {
            const int bc = ks * 64 + 16 * (lane >> 4);
            bf16x8 a[4], b[4];
            for (int j = 0; j < 4; ++j)
                a[j] = *(const bf16x8*)lds_swz(&At[cur][0], wr*64 + j*16 + (lane&15), bc);
            for (int i = 0; i < 4; ++i)
                b[i] = *(const bf16x8*)lds_swz(&Bt[cur][0], wc*64 + i*16 + (lane&15), bc);
            for (int i = 0; i < 4; ++i)
                for (int j = 0; j < 4; ++j)
                    acc[i][j] = MFMA16(b[i], a[j], acc[i][j]);
        }
        cur ^= 1;
        if (kt + 1 < E_/64) __syncthreads();
    }

    const int mW = m0 + wr*64;
    for (int i = 0; i < 4; ++i) {
        const int n4 = n0 + wc*64 + i*16 + (lane >> 4) * 4;   // 4 consecutive n
        const float4 b4 = *reinterpret_cast<const float4*>(&bias[n4]);
        const float* bp = reinterpret_cast<const float*>(&b4);
        if constexpr (MODE == 0) {
            const int t = n4 >> 10, h = (n4 >> 6) & 15, d0 = n4 & 63;
            for (int j = 0; j < 4; ++j) {
                const int m = mW + j*16 + (lane & 15);
                const int bb_i = m >> 11, s = m & 2047;
                if (t == 2) {
                    for (int r = 0; r < 4; ++r)
                        Vt[(((size_t)(bb_i*H_ + h))*DH_ + d0 + r)*S_ + s] =
                            (bf16)(acc[i][j][r] + bp[r]);
                } else {
                    bf16* dst = (t == 0) ? Qb : Kb;
                    const float sc = (t == 0) ? QSCALE_ : 1.0f;
                    bf16x4 o;
                    for (int r = 0; r < 4; ++r)
                        o[r] = (bf16)((acc[i][j][r] + bp[r]) * sc);
                    *reinterpret_cast<bf16x4*>(
                        dst + (((size_t)(bb_i*H_ + h))*S_ + s)*DH_ + d0) = o;
                }
            }
        } else {
            for (int j = 0; j < 4; ++j) {
                const int m = mW + j*16 + (lane & 15);
                float4 o;
                o.x = acc[i][j][0] + bp[0];
                o.y = acc[i][j][1] + bp[1];
                o.z = acc[i][j][2] + bp[2];
                o.w = acc[i][j][3] + bp[3];
                *reinterpret_cast<float4*>(out + (size_t)m * E_ + n4) = o;
            }
        }
    }
}

// ---------------- pass 1: l_k = sum_q exp2(S'[q,k]); fold 1/l into V^T -----------
__global__ __launch_bounds__(256) void k_colsum(
    const bf16* __restrict__ Qb, const bf16* __restrict__ Kb,
    bf16* __restrict__ Vt)
{
    __shared__ __align__(16) bf16 Kl[128*64];
    __shared__ __align__(16) bf16 Ql[2][128*64];
    __shared__ float rlbuf[128];
    const int tid = threadIdx.x, lane = tid & 63, w = tid >> 6;
    const int g = blockIdx.x, xcd = g & 7, li = g >> 3;
    const int bh = xcd * 4 + (li >> 4);          // same-bh blocks share an XCD
    const int k0 = (li & 15) * 128;
    const bf16* Kbase = Kb + ((size_t)bh * S_ + k0) * DH_;
    const bf16* Qbase = Qb + (size_t)bh * S_ * DH_;

    for (int j = 0; j < 4; ++j) {
        const int idx = j*256 + tid, row = idx >> 3;
        const int colx = ((idx & 7) * 8) ^ (F_(row) * 8);
        gload_lds16(Kbase + (size_t)row * DH_ + colx, &Kl[(j*256 + w*64) * 8]);
    }
    auto stageQ = [&](int qt, int buf) {
        for (int j = 0; j < 4; ++j) {
            const int idx = j*256 + tid, row = idx >> 3;
            const int colx = ((idx & 7) * 8) ^ (F_(row) * 8);
            gload_lds16(Qbase + (size_t)(qt*128 + row) * DH_ + colx,
                        &Ql[buf][(j*256 + w*64) * 8]);
        }
    };
    stageQ(0, 0);
    __syncthreads();

    bf16x8 bk[2][2];
    for (int ks = 0; ks < 2; ++ks) {
        const int bc = ks * 64 + 16 * (lane >> 4);
        bk[ks][0] = *(const bf16x8*)lds_swz(Kl, w*32 + (lane&15), bc);
        bk[ks][1] = *(const bf16x8*)lds_swz(Kl, w*32 + 16 + (lane&15), bc);
    }

    float lsum0 = 0.f, lsum1 = 0.f;
    int cur = 0;
    for (int qt = 0; qt < S_/128; ++qt) {
        if (qt + 1 < S_/128) stageQ(qt + 1, cur ^ 1);
        #pragma unroll
        for (int qi = 0; qi < 8; ++qi) {
            f32x4 s0 = {}, s1 = {};
            for (int ks = 0; ks < 2; ++ks) {
                const int bc = ks * 64 + 16 * (lane >> 4);
                bf16x8 aq = *(const bf16x8*)lds_swz(&Ql[cur][0], qi*16 + (lane&15), bc);
                s0 = MFMA16(aq, bk[ks][0], s0);
                s1 = MFMA16(aq, bk[ks][1], s1);
            }
            for (int r = 0; r < 4; ++r) {
                lsum0 += exp2f(s0[r]);
                lsum1 += exp2f(s1[r]);
            }
        }
        cur ^= 1;
        if (qt + 1 < S_/128) __syncthreads();
    }
    lsum0 += __shfl_xor(lsum0, 16); lsum0 += __shfl_xor(lsum0, 32);
    lsum1 += __shfl_xor(lsum1, 16); lsum1 += __shfl_xor(lsum1, 32);
    if (lane < 16) {
        rlbuf[w*32 + lane]      = 1.0f / lsum0;
        rlbuf[w*32 + 16 + lane] = 1.0f / lsum1;
    }
    __syncthreads();

    // scale V^T columns [k0, k0+128) for all 64 d rows (disjoint per block)
    bf16* Vb = Vt + (size_t)bh * DH_ * S_ + k0;
    const int d = tid >> 2, kk = (tid & 3) * 32;
    for (int c = 0; c < 4; ++c) {
        bf16x8* p = reinterpret_cast<bf16x8*>(Vb + (size_t)d * S_ + kk + c*8);
        bf16x8 v = *p, o;
        for (int jj = 0; jj < 8; ++jj)
            o[jj] = (bf16)((float)v[jj] * rlbuf[kk + c*8 + jj]);
        *p = o;
    }
}

// ---------------- pass 2: O = exp2(S') @ V'; swapped QK^T, packed P spill --------
__global__ __launch_bounds__(256) void k_attn(
    const bf16* __restrict__ Qb, const bf16* __restrict__ Kb,
    const bf16* __restrict__ Vt, bf16* __restrict__ AO)
{
    __shared__ __align__(16) bf16 Ql[128*64];
    __shared__ __align__(16) bf16 Kl[2][64*64];
    __shared__ __align__(16) bf16 Vl[2][64*64];
    __shared__ __align__(16) bf16 Pl[4][32*64];
    const int tid = threadIdx.x, lane = tid & 63, w = tid >> 6;
    const int g = blockIdx.x, xcd = g & 7, li = g >> 3;
    const int bh = xcd * 4 + (li >> 4);
    const int q0 = (li & 15) * 128;
    const bf16* Qbase = Qb + ((size_t)bh * S_ + q0) * DH_;
    const bf16* Kbase = Kb + (size_t)bh * S_ * DH_;
    const bf16* Vbase = Vt + (size_t)bh * DH_ * S_;
    bf16* Plw = &Pl[w][0];

    for (int j = 0; j < 4; ++j) {
        const int idx = j*256 + tid, row = idx >> 3;
        const int colx = ((idx & 7) * 8) ^ (F_(row) * 8);
        gload_lds16(Qbase + (size_t)row * DH_ + colx, &Ql[(j*256 + w*64) * 8]);
    }
    auto stageKV = [&](int kt, int buf) {
        for (int j = 0; j < 2; ++j) {
            const int idx = j*256 + tid, row = idx >> 3;
            const int colx = ((idx & 7) * 8) ^ (F_(row) * 8);
            gload_lds16(Kbase + (size_t)(kt*64 + row) * DH_ + colx,
                        &Kl[buf][(j*256 + w*64) * 8]);
            gload_lds16(Vbase + (size_t)row * S_ + kt*64 + colx,
                        &Vl[buf][(j*256 + w*64) * 8]);
        }
    };
    stageKV(0, 0);
    __syncthreads();

    f32x4 oacc[2][4] = {};
    int cur = 0;
    for (int kt = 0; kt < S_/64; ++kt) {
        if (kt + 1 < S_/64) stageKV(kt + 1, cur ^ 1);

        // QK^T swapped: S^T[k][q], lane holds 4 consecutive k for one q
        f32x4 sacc[4][2] = {};
        for (int ks = 0; ks < 2; ++ks) {
            const int bc = ks * 64 + 16 * (lane >> 4);
            bf16x8 ak[4], bq[2];
            for (int kf = 0; kf < 4; ++kf)
                ak[kf] = *(const bf16x8*)lds_swz(&Kl[cur][0], kf*16 + (lane&15), bc);
            for (int qi = 0; qi < 2; ++qi)
                bq[qi] = *(const bf16x8*)lds_swz(Ql, w*32 + qi*16 + (lane&15), bc);
            for (int kf = 0; kf < 4; ++kf)
                for (int qi = 0; qi < 2; ++qi)
                    sacc[kf][qi] = MFMA16(ak[kf], bq[qi], sacc[kf][qi]);
        }

        // P = exp2(s') -> packed b64 writes into per-wave Pl [32q][64k]
        for (int kf = 0; kf < 4; ++kf)
            for (int qi = 0; qi < 2; ++qi) {
                const int row = qi*16 + (lane & 15);
                uint2 pw;
                pw.x = cvt_pk_bf16(exp2f(sacc[kf][qi][0]), exp2f(sacc[kf][qi][1]));
                pw.y = cvt_pk_bf16(exp2f(sacc[kf][qi][2]), exp2f(sacc[kf][qi][3]));
                *(uint2*)lds_swz(Plw, row, kf*32 + (lane >> 4) * 8) = pw;
            }
        // Pl per-wave private: lgkmcnt ordering suffices, no barrier

        // PV: O^T frags — out rows = d, cols = q (packed epilogue stores)
        for (int ks = 0; ks < 2; ++ks) {
            const int bc = ks * 64 + 16 * (lane >> 4);
            bf16x8 ap[2], bv[4];
            for (int i = 0; i < 2; ++i)
                ap[i] = *(const bf16x8*)lds_swz(Plw, i*16 + (lane&15), bc);
            for (int jf = 0; jf < 4; ++jf)
                bv[jf] = *(const bf16x8*)lds_swz(&Vl[cur][0], jf*16 + (lane&15), bc);
            for (int i = 0; i < 2; ++i)
                for (int jf = 0; jf < 4; ++jf)
                    oacc[i][jf] = MFMA16(bv[jf], ap[i], oacc[i][jf]);
        }
        cur ^= 1;
        if (kt + 1 < S_/64) __syncthreads();
    }

    // epilogue: AO[b, q, h*64+d], 4 consecutive d -> 8B stores
    const int b = bh >> 4, h = bh & 15;
    for (int i = 0; i < 2; ++i)
        for (int jf = 0; jf < 4; ++jf) {
            const int d0 = jf*16 + (lane >> 4) * 4;
            const int q = q0 + w*32 + i*16 + (lane & 15);
            bf16x4 o;
            for (int r = 0; r < 4; ++r) o[r] = (bf16)oacc[i][jf][r];
            *reinterpret_cast<bf16x4*>(
                AO + ((size_t)(b*S_ + q))*E_ + h*DH_ + d0) = o;
        }
}

extern "C" void kernel_launch(void* const* d_in, const int* in_sizes, int n_in,
                              void* d_out, int out_size, void* d_ws, size_t ws_size,
                              hipStream_t stream) {
    const float* input = (const float*)d_in[0];
    const float* Wqkv  = (const float*)d_in[1];
    const float* bqkv  = (const float*)d_in[2];
    const float* Wo    = (const float*)d_in[3];
    const float* bo    = (const float*)d_in[4];
    float* out = (float*)d_out;

    char* ws = (char*)d_ws;
    bf16*  Xb   = (bf16*) (ws + 0);
    bf16*  Wqb  = (bf16*) (ws + 8388608);
    bf16*  Wob  = (bf16*) (ws + 14680064);
    bf16*  Qb   = (bf16*) (ws + 16777216);
    bf16*  Kb   = (bf16*) (ws + 25165824);
    bf16*  Vtg  = (bf16*) (ws + 33554432);
    bf16*  AO   = (bf16*) (ws + 41943040);

    k_f2b3<<<(NX_ + NW_ + NWO_) / 1024, 256, 0, stream>>>(
        input, Wqkv, Wo, Xb, Wqb, Wob);

    k_gemm<0><<<768, 256, 0, stream>>>(Xb, Wqb, bqkv, Qb, Kb, Vtg, nullptr);

    k_colsum<<<512, 256, 0, stream>>>(Qb, Kb, Vtg);

    k_attn<<<512, 256, 0, stream>>>(Qb, Kb, Vtg, AO);

    k_gemm<1><<<256, 256, 0, stream>>>(AO, Wob, bo, nullptr, nullptr, nullptr, out);
}

// Round 5
// 172.843 us; speedup vs baseline: 1.1635x; 1.1635x over previous
//
#include <hip/hip_runtime.h>
#include <math.h>

#define B_ 2
#define S_ 2048
#define E_ 1024
#define H_ 16
#define DH_ 64
#define NE3_ 3072
#define MTOT_ (B_*S_)
#define QSCALE_ 0.18033688011112042f   // 0.125 * log2(e); P = exp2(s')

typedef __bf16 bf16;
typedef bf16 bf16x8 __attribute__((ext_vector_type(8)));
typedef bf16 bf16x4 __attribute__((ext_vector_type(4)));
typedef float f32x4 __attribute__((ext_vector_type(4)));

#define MFMA16(a,b,c) __builtin_amdgcn_mfma_f32_16x16x32_bf16(a,b,c,0,0,0)

// XOR swizzle: rows are 128B; slot = 16B unit.
#define F_(r) ((((r) & 7) ^ (((r) >> 3) & 7)))

__device__ inline void* lds_swz(void* base, int row, int bytecol) {
    return (char*)base + row * 128 + (bytecol ^ (F_(row) << 4));
}

__device__ inline unsigned cvt_pk_bf16(float lo, float hi) {
    unsigned r;
    asm("v_cvt_pk_bf16_f32 %0, %1, %2" : "=v"(r) : "v"(lo), "v"(hi));
    return r;
}

// hardware 2^x: single v_exp_f32 (exp2f is libm-precise, ~10 VALU ops)
__device__ inline float exp2_hw(float x) {
    float r;
    asm("v_exp_f32 %0, %1" : "=v"(r) : "v"(x));
    return r;
}

__device__ inline void gload_lds16(const void* g, void* l) {
    __builtin_amdgcn_global_load_lds(
        (const __attribute__((address_space(1))) void*)g,
        (__attribute__((address_space(3))) void*)l, 16, 0, 0);
}

// ---------------- fp32 -> bf16 convert, all three arrays in one launch --------
#define NX_ (MTOT_*E_)
#define NW_ (NE3_*E_)
#define NWO_ (E_*E_)
__global__ void k_f2b3(const float* __restrict__ x, const float* __restrict__ wq,
                       const float* __restrict__ wo,
                       bf16* __restrict__ xb, bf16* __restrict__ wqb,
                       bf16* __restrict__ wob) {
    const int i = blockIdx.x * 256 + threadIdx.x;
    const int idx = i * 4;
    const float* src; bf16* dst; int off;
    if (idx < NX_)            { src = x;  dst = xb;  off = idx; }
    else if (idx < NX_ + NW_) { src = wq; dst = wqb; off = idx - NX_; }
    else                      { src = wo; dst = wob; off = idx - NX_ - NW_; }
    float4 f = *reinterpret_cast<const float4*>(src + off);
    bf16x4 o;
    o[0] = (bf16)f.x; o[1] = (bf16)f.y; o[2] = (bf16)f.z; o[3] = (bf16)f.w;
    *reinterpret_cast<bf16x4*>(dst + off) = o;
}

// ---------------- GEMM: C = A @ W^T (+bias), swapped orientation ----------------
template<int MODE>
__global__ __launch_bounds__(256) void k_gemm(
    const bf16* __restrict__ A, const bf16* __restrict__ W,
    const float* __restrict__ bias,
    bf16* __restrict__ Qb, bf16* __restrict__ Kb, bf16* __restrict__ Vt,
    float* __restrict__ out)
{
    __shared__ __align__(16) bf16 At[2][128*64];
    __shared__ __align__(16) bf16 Bt[2][128*64];
    const int tid = threadIdx.x, lane = tid & 63, w = tid >> 6;
    const int wr = w >> 1, wc = w & 1;
    const int g = blockIdx.x;
    const int nxw = (MODE == 0 ? 3 : 1);
    const int xcd = g & 7, li = g >> 3;
    const int m0 = (li & 31) * 128;
    const int n0 = (xcd * nxw + (li >> 5)) * 128;

    f32x4 acc[4][4] = {};
    const int lrow = lane >> 3, lcol = (lane & 7) * 8;

    auto stage = [&](int k0, int buf) {
        for (int c4 = 0; c4 < 4; ++c4) {
            const int c = w * 4 + c4;
            const int row = c * 8 + lrow;
            const int colx = lcol ^ (F_(row) * 8);
            gload_lds16(A + (size_t)(m0 + row) * E_ + k0 + colx, &At[buf][c * 512]);
            gload_lds16(W + (size_t)(n0 + row) * E_ + k0 + colx, &Bt[buf][c * 512]);
        }
    };
    stage(0, 0);
    __syncthreads();

    int cur = 0;
    for (int kt = 0; kt < E_/64; ++kt) {
        if (kt + 1 < E_/64) stage((kt + 1) * 64, cur ^ 1);
        for (int ks = 0; ks < 2; ++ks) {
            const int bc = ks * 64 + 16 * (lane >> 4);
            bf16x8 a[4], b[4];
            for (int j = 0; j < 4; ++j)
                a[j] = *(const bf16x8*)lds_swz(&At[cur][0], wr*64 + j*16 + (lane&15), bc);
            for (int i = 0; i < 4; ++i)
                b[i] = *(const bf16x8*)lds_swz(&Bt[cur][0], wc*64 + i*16 + (lane&15), bc);
            for (int i = 0; i < 4; ++i)
                for (int j = 0; j < 4; ++j)
                    acc[i][j] = MFMA16(b[i], a[j], acc[i][j]);
        }
        cur ^= 1;
        if (kt + 1 < E_/64) __syncthreads();
    }

    const int mW = m0 + wr*64;
    for (int i = 0; i < 4; ++i) {
        const int n4 = n0 + wc*64 + i*16 + (lane >> 4) * 4;
        const float4 b4 = *reinterpret_cast<const float4*>(&bias[n4]);
        const float* bp = reinterpret_cast<const float*>(&b4);
        if constexpr (MODE == 0) {
            const int t = n4 >> 10, h = (n4 >> 6) & 15, d0 = n4 & 63;
            for (int j = 0; j < 4; ++j) {
                const int m = mW + j*16 + (lane & 15);
                const int bb_i = m >> 11, s = m & 2047;
                if (t == 2) {
                    for (int r = 0; r < 4; ++r)
                        Vt[(((size_t)(bb_i*H_ + h))*DH_ + d0 + r)*S_ + s] =
                            (bf16)(acc[i][j][r] + bp[r]);
                } else {
                    bf16* dst = (t == 0) ? Qb : Kb;
                    const float sc = (t == 0) ? QSCALE_ : 1.0f;
                    bf16x4 o;
                    for (int r = 0; r < 4; ++r)
                        o[r] = (bf16)((acc[i][j][r] + bp[r]) * sc);
                    *reinterpret_cast<bf16x4*>(
                        dst + (((size_t)(bb_i*H_ + h))*S_ + s)*DH_ + d0) = o;
                }
            }
        } else {
            for (int j = 0; j < 4; ++j) {
                const int m = mW + j*16 + (lane & 15);
                float4 o;
                o.x = acc[i][j][0] + bp[0];
                o.y = acc[i][j][1] + bp[1];
                o.z = acc[i][j][2] + bp[2];
                o.w = acc[i][j][3] + bp[3];
                *reinterpret_cast<float4*>(out + (size_t)m * E_ + n4) = o;
            }
        }
    }
}

// ---------------- pass 1: l_k = sum_q exp2(S'[q,k]); fold 1/l into V^T -----------
__global__ __launch_bounds__(256) void k_colsum(
    const bf16* __restrict__ Qb, const bf16* __restrict__ Kb,
    bf16* __restrict__ Vt)
{
    __shared__ __align__(16) bf16 Kl[128*64];
    __shared__ __align__(16) bf16 Ql[2][128*64];
    __shared__ float rlbuf[128];
    const int tid = threadIdx.x, lane = tid & 63, w = tid >> 6;
    const int g = blockIdx.x, xcd = g & 7, li = g >> 3;
    const int bh = xcd * 4 + (li >> 4);
    const int k0 = (li & 15) * 128;
    const bf16* Kbase = Kb + ((size_t)bh * S_ + k0) * DH_;
    const bf16* Qbase = Qb + (size_t)bh * S_ * DH_;

    for (int j = 0; j < 4; ++j) {
        const int idx = j*256 + tid, row = idx >> 3;
        const int colx = ((idx & 7) * 8) ^ (F_(row) * 8);
        gload_lds16(Kbase + (size_t)row * DH_ + colx, &Kl[(j*256 + w*64) * 8]);
    }
    auto stageQ = [&](int qt, int buf) {
        for (int j = 0; j < 4; ++j) {
            const int idx = j*256 + tid, row = idx >> 3;
            const int colx = ((idx & 7) * 8) ^ (F_(row) * 8);
            gload_lds16(Qbase + (size_t)(qt*128 + row) * DH_ + colx,
                        &Ql[buf][(j*256 + w*64) * 8]);
        }
    };
    stageQ(0, 0);
    __syncthreads();

    bf16x8 bk[2][2];
    for (int ks = 0; ks < 2; ++ks) {
        const int bc = ks * 64 + 16 * (lane >> 4);
        bk[ks][0] = *(const bf16x8*)lds_swz(Kl, w*32 + (lane&15), bc);
        bk[ks][1] = *(const bf16x8*)lds_swz(Kl, w*32 + 16 + (lane&15), bc);
    }

    float lsum0 = 0.f, lsum1 = 0.f;
    int cur = 0;
    for (int qt = 0; qt < S_/128; ++qt) {
        if (qt + 1 < S_/128) stageQ(qt + 1, cur ^ 1);
        #pragma unroll
        for (int qi = 0; qi < 8; ++qi) {
            f32x4 s0 = {}, s1 = {};
            for (int ks = 0; ks < 2; ++ks) {
                const int bc = ks * 64 + 16 * (lane >> 4);
                bf16x8 aq = *(const bf16x8*)lds_swz(&Ql[cur][0], qi*16 + (lane&15), bc);
                s0 = MFMA16(aq, bk[ks][0], s0);
                s1 = MFMA16(aq, bk[ks][1], s1);
            }
            for (int r = 0; r < 4; ++r) {
                lsum0 += exp2_hw(s0[r]);
                lsum1 += exp2_hw(s1[r]);
            }
        }
        cur ^= 1;
        if (qt + 1 < S_/128) __syncthreads();
    }
    lsum0 += __shfl_xor(lsum0, 16); lsum0 += __shfl_xor(lsum0, 32);
    lsum1 += __shfl_xor(lsum1, 16); lsum1 += __shfl_xor(lsum1, 32);
    if (lane < 16) {
        rlbuf[w*32 + lane]      = 1.0f / lsum0;
        rlbuf[w*32 + 16 + lane] = 1.0f / lsum1;
    }
    __syncthreads();

    bf16* Vb = Vt + (size_t)bh * DH_ * S_ + k0;
    const int d = tid >> 2, kk = (tid & 3) * 32;
    for (int c = 0; c < 4; ++c) {
        bf16x8* p = reinterpret_cast<bf16x8*>(Vb + (size_t)d * S_ + kk + c*8);
        bf16x8 v = *p, o;
        for (int jj = 0; jj < 8; ++jj)
            o[jj] = (bf16)((float)v[jj] * rlbuf[kk + c*8 + jj]);
        *p = o;
    }
}

// ---------------- pass 2: O = exp2(S') @ V'; 64 q per wave, Q hoisted ----------
__global__ __launch_bounds__(256) void k_attn(
    const bf16* __restrict__ Qb, const bf16* __restrict__ Kb,
    const bf16* __restrict__ Vt, bf16* __restrict__ AO)
{
    // layout: [0,32768) Ql (256 rows x 128B) -> reused as per-wave Pl after hoist
    //         [32768,49152) Kl dbuf; [49152,65536) Vl dbuf
    __shared__ __align__(16) char smem[65536];
    const int tid = threadIdx.x, lane = tid & 63, w = tid >> 6;
    const int g = blockIdx.x, xcd = g & 7, li = g >> 3;
    const int bh = xcd * 4 + (li >> 3);
    const int q0 = (li & 7) * 256;
    const bf16* Qbase = Qb + ((size_t)bh * S_ + q0) * DH_;
    const bf16* Kbase = Kb + (size_t)bh * S_ * DH_;
    const bf16* Vbase = Vt + (size_t)bh * DH_ * S_;
    char* QP  = smem;
    char* Plw = smem + w * 8192;   // wave w's Q rows == wave w's Pl region

    // stage Q (256 rows x 64 dh)
    for (int j = 0; j < 8; ++j) {
        const int idx = j*256 + tid, row = idx >> 3;
        const int colx = ((idx & 7) * 8) ^ (F_(row) * 8);
        gload_lds16(Qbase + (size_t)row * DH_ + colx, QP + (j*256 + w*64) * 16);
    }
    auto stageKV = [&](int kt, int buf) {
        for (int j = 0; j < 2; ++j) {
            const int idx = j*256 + tid, row = idx >> 3;
            const int colx = ((idx & 7) * 8) ^ (F_(row) * 8);
            gload_lds16(Kbase + (size_t)(kt*64 + row) * DH_ + colx,
                        smem + 32768 + buf*8192 + (j*256 + w*64) * 16);
            gload_lds16(Vbase + (size_t)row * S_ + kt*64 + colx,
                        smem + 49152 + buf*8192 + (j*256 + w*64) * 16);
        }
    };
    stageKV(0, 0);
    __syncthreads();

    // hoist Q fragments: bq[qi][ks], wave-private rows -> 32 VGPRs
    bf16x8 bq[4][2];
    for (int qi = 0; qi < 4; ++qi)
        for (int ks = 0; ks < 2; ++ks)
            bq[qi][ks] = *(const bf16x8*)lds_swz(QP, w*64 + qi*16 + (lane&15),
                                                 ks*64 + 16*(lane>>4));

    f32x4 oacc[4][4] = {};
    int cur = 0;
    for (int kt = 0; kt < S_/64; ++kt) {
        if (kt + 1 < S_/64) stageKV(kt + 1, cur ^ 1);
        char* Kc = smem + 32768 + cur*8192;
        char* Vc = smem + 49152 + cur*8192;

        // swapped QK^T, kf-sliced; P = exp2(s') -> Plw [64q][64k]
        for (int kf = 0; kf < 4; ++kf) {
            f32x4 sacc[4] = {};
            for (int ks = 0; ks < 2; ++ks) {
                bf16x8 ak = *(const bf16x8*)lds_swz(Kc, kf*16 + (lane&15),
                                                    ks*64 + 16*(lane>>4));
                for (int qi = 0; qi < 4; ++qi)
                    sacc[qi] = MFMA16(ak, bq[qi][ks], sacc[qi]);
            }
            for (int qi = 0; qi < 4; ++qi) {
                uint2 pw;
                pw.x = cvt_pk_bf16(exp2_hw(sacc[qi][0]), exp2_hw(sacc[qi][1]));
                pw.y = cvt_pk_bf16(exp2_hw(sacc[qi][2]), exp2_hw(sacc[qi][3]));
                *(uint2*)lds_swz(Plw, qi*16 + (lane&15), kf*32 + (lane>>4)*8) = pw;
            }
        }

        // PV: O^T[64d][64q] += V'^T-tile @ P^T (4x4 register blocking)
        for (int ks = 0; ks < 2; ++ks) {
            const int bc = ks*64 + 16*(lane>>4);
            bf16x8 av[4], bp[4];
            for (int df = 0; df < 4; ++df)
                av[df] = *(const bf16x8*)lds_swz(Vc, df*16 + (lane&15), bc);
            for (int qi = 0; qi < 4; ++qi)
                bp[qi] = *(const bf16x8*)lds_swz(Plw, qi*16 + (lane&15), bc);
            for (int df = 0; df < 4; ++df)
                for (int qi = 0; qi < 4; ++qi)
                    oacc[df][qi] = MFMA16(av[df], bp[qi], oacc[df][qi]);
        }
        cur ^= 1;
        if (kt + 1 < S_/64) __syncthreads();
    }

    // epilogue: AO[b, q, h*64+d], 4 consecutive d -> 8B stores
    const int b = bh >> 4, h = bh & 15;
    for (int df = 0; df < 4; ++df)
        for (int qi = 0; qi < 4; ++qi) {
            const int d0 = df*16 + (lane >> 4) * 4;
            const int q = q0 + w*64 + qi*16 + (lane & 15);
            bf16x4 o;
            for (int r = 0; r < 4; ++r) o[r] = (bf16)oacc[df][qi][r];
            *reinterpret_cast<bf16x4*>(
                AO + ((size_t)(b*S_ + q))*E_ + h*DH_ + d0) = o;
        }
}

extern "C" void kernel_launch(void* const* d_in, const int* in_sizes, int n_in,
                              void* d_out, int out_size, void* d_ws, size_t ws_size,
                              hipStream_t stream) {
    const float* input = (const float*)d_in[0];
    const float* Wqkv  = (const float*)d_in[1];
    const float* bqkv  = (const float*)d_in[2];
    const float* Wo    = (const float*)d_in[3];
    const float* bo    = (const float*)d_in[4];
    float* out = (float*)d_out;

    char* ws = (char*)d_ws;
    bf16*  Xb   = (bf16*) (ws + 0);
    bf16*  Wqb  = (bf16*) (ws + 8388608);
    bf16*  Wob  = (bf16*) (ws + 14680064);
    bf16*  Qb   = (bf16*) (ws + 16777216);
    bf16*  Kb   = (bf16*) (ws + 25165824);
    bf16*  Vtg  = (bf16*) (ws + 33554432);
    bf16*  AO   = (bf16*) (ws + 41943040);

    k_f2b3<<<(NX_ + NW_ + NWO_) / 1024, 256, 0, stream>>>(
        input, Wqkv, Wo, Xb, Wqb, Wob);

    k_gemm<0><<<768, 256, 0, stream>>>(Xb, Wqb, bqkv, Qb, Kb, Vtg, nullptr);

    k_colsum<<<512, 256, 0, stream>>>(Qb, Kb, Vtg);

    k_attn<<<256, 256, 0, stream>>>(Qb, Kb, Vtg, AO);

    k_gemm<1><<<256, 256, 0, stream>>>(AO, Wob, bo, nullptr, nullptr, nullptr, out);
}

// Round 6
// 169.188 us; speedup vs baseline: 1.1887x; 1.0216x over previous
//
#include <hip/hip_runtime.h>
#include <math.h>

#define B_ 2
#define S_ 2048
#define E_ 1024
#define H_ 16
#define DH_ 64
#define NE3_ 3072
#define MTOT_ (B_*S_)
#define QSCALE_ 0.18033688011112042f   // 0.125 * log2(e); P = exp2(s')

typedef __bf16 bf16;
typedef bf16 bf16x8 __attribute__((ext_vector_type(8)));
typedef bf16 bf16x4 __attribute__((ext_vector_type(4)));
typedef float f32x4 __attribute__((ext_vector_type(4)));

#define MFMA16(a,b,c) __builtin_amdgcn_mfma_f32_16x16x32_bf16(a,b,c,0,0,0)

// XOR swizzle: rows are 128B; slot = 16B unit.
#define F_(r) ((((r) & 7) ^ (((r) >> 3) & 7)))

__device__ inline void* lds_swz(void* base, int row, int bytecol) {
    return (char*)base + row * 128 + (bytecol ^ (F_(row) << 4));
}

__device__ inline unsigned cvt_pk_bf16(float lo, float hi) {
    unsigned r;
    asm("v_cvt_pk_bf16_f32 %0, %1, %2" : "=v"(r) : "v"(lo), "v"(hi));
    return r;
}

// hardware 2^x: single v_exp_f32
__device__ inline float exp2_hw(float x) {
    float r;
    asm("v_exp_f32 %0, %1" : "=v"(r) : "v"(x));
    return r;
}

__device__ inline void gload_lds16(const void* g, void* l) {
    __builtin_amdgcn_global_load_lds(
        (const __attribute__((address_space(1))) void*)g,
        (__attribute__((address_space(3))) void*)l, 16, 0, 0);
}

// ---------------- fp32 -> bf16 convert, all three arrays in one launch --------
#define NX_ (MTOT_*E_)
#define NW_ (NE3_*E_)
#define NWO_ (E_*E_)
__global__ void k_f2b3(const float* __restrict__ x, const float* __restrict__ wq,
                       const float* __restrict__ wo,
                       bf16* __restrict__ xb, bf16* __restrict__ wqb,
                       bf16* __restrict__ wob) {
    const int i = blockIdx.x * 256 + threadIdx.x;
    const int idx = i * 4;
    const float* src; bf16* dst; int off;
    if (idx < NX_)            { src = x;  dst = xb;  off = idx; }
    else if (idx < NX_ + NW_) { src = wq; dst = wqb; off = idx - NX_; }
    else                      { src = wo; dst = wob; off = idx - NX_ - NW_; }
    float4 f = *reinterpret_cast<const float4*>(src + off);
    bf16x4 o;
    o[0] = (bf16)f.x; o[1] = (bf16)f.y; o[2] = (bf16)f.z; o[3] = (bf16)f.w;
    *reinterpret_cast<bf16x4*>(dst + off) = o;
}

// ---------------- GEMM: C = A @ W^T (+bias), swapped orientation ----------------
template<int MODE>
__global__ __launch_bounds__(256) void k_gemm(
    const bf16* __restrict__ A, const bf16* __restrict__ W,
    const float* __restrict__ bias,
    bf16* __restrict__ Qb, bf16* __restrict__ Kb, bf16* __restrict__ Vt,
    float* __restrict__ out)
{
    __shared__ __align__(16) bf16 At[2][128*64];
    __shared__ __align__(16) bf16 Bt[2][128*64];
    const int tid = threadIdx.x, lane = tid & 63, w = tid >> 6;
    const int wr = w >> 1, wc = w & 1;
    const int g = blockIdx.x;
    const int nxw = (MODE == 0 ? 3 : 1);
    const int xcd = g & 7, li = g >> 3;
    const int m0 = (li & 31) * 128;
    const int n0 = (xcd * nxw + (li >> 5)) * 128;

    f32x4 acc[4][4] = {};
    const int lrow = lane >> 3, lcol = (lane & 7) * 8;

    auto stage = [&](int k0, int buf) {
        for (int c4 = 0; c4 < 4; ++c4) {
            const int c = w * 4 + c4;
            const int row = c * 8 + lrow;
            const int colx = lcol ^ (F_(row) * 8);
            gload_lds16(A + (size_t)(m0 + row) * E_ + k0 + colx, &At[buf][c * 512]);
            gload_lds16(W + (size_t)(n0 + row) * E_ + k0 + colx, &Bt[buf][c * 512]);
        }
    };
    stage(0, 0);
    __syncthreads();

    int cur = 0;
    for (int kt = 0; kt < E_/64; ++kt) {
        if (kt + 1 < E_/64) stage((kt + 1) * 64, cur ^ 1);
        for (int ks = 0; ks < 2; ++ks) {
            const int bc = ks * 64 + 16 * (lane >> 4);
            bf16x8 a[4], b[4];
            for (int j = 0; j < 4; ++j)
                a[j] = *(const bf16x8*)lds_swz(&At[cur][0], wr*64 + j*16 + (lane&15), bc);
            for (int i = 0; i < 4; ++i)
                b[i] = *(const bf16x8*)lds_swz(&Bt[cur][0], wc*64 + i*16 + (lane&15), bc);
            for (int i = 0; i < 4; ++i)
                for (int j = 0; j < 4; ++j)
                    acc[i][j] = MFMA16(b[i], a[j], acc[i][j]);
        }
        cur ^= 1;
        if (kt + 1 < E_/64) __syncthreads();
    }

    const int mW = m0 + wr*64;
    for (int i = 0; i < 4; ++i) {
        const int n4 = n0 + wc*64 + i*16 + (lane >> 4) * 4;
        const float4 b4 = *reinterpret_cast<const float4*>(&bias[n4]);
        const float* bp = reinterpret_cast<const float*>(&b4);
        if constexpr (MODE == 0) {
            const int t = n4 >> 10, h = (n4 >> 6) & 15, d0 = n4 & 63;
            for (int j = 0; j < 4; ++j) {
                const int m = mW + j*16 + (lane & 15);
                const int bb_i = m >> 11, s = m & 2047;
                if (t == 2) {
                    for (int r = 0; r < 4; ++r)
                        Vt[(((size_t)(bb_i*H_ + h))*DH_ + d0 + r)*S_ + s] =
                            (bf16)(acc[i][j][r] + bp[r]);
                } else {
                    bf16* dst = (t == 0) ? Qb : Kb;
                    const float sc = (t == 0) ? QSCALE_ : 1.0f;
                    bf16x4 o;
                    for (int r = 0; r < 4; ++r)
                        o[r] = (bf16)((acc[i][j][r] + bp[r]) * sc);
                    *reinterpret_cast<bf16x4*>(
                        dst + (((size_t)(bb_i*H_ + h))*S_ + s)*DH_ + d0) = o;
                }
            }
        } else {
            for (int j = 0; j < 4; ++j) {
                const int m = mW + j*16 + (lane & 15);
                float4 o;
                o.x = acc[i][j][0] + bp[0];
                o.y = acc[i][j][1] + bp[1];
                o.z = acc[i][j][2] + bp[2];
                o.w = acc[i][j][3] + bp[3];
                *reinterpret_cast<float4*>(out + (size_t)m * E_ + n4) = o;
            }
        }
    }
}

// ---------------- pass 1: l_k = sum_q exp2(S'[q,k]); fold 1/l into V^T -----------
__global__ __launch_bounds__(256) void k_colsum(
    const bf16* __restrict__ Qb, const bf16* __restrict__ Kb,
    bf16* __restrict__ Vt)
{
    __shared__ __align__(16) bf16 Kl[128*64];
    __shared__ __align__(16) bf16 Ql[2][128*64];
    __shared__ float rlbuf[128];
    const int tid = threadIdx.x, lane = tid & 63, w = tid >> 6;
    const int g = blockIdx.x, xcd = g & 7, li = g >> 3;
    const int bh = xcd * 4 + (li >> 4);
    const int k0 = (li & 15) * 128;
    const bf16* Kbase = Kb + ((size_t)bh * S_ + k0) * DH_;
    const bf16* Qbase = Qb + (size_t)bh * S_ * DH_;

    for (int j = 0; j < 4; ++j) {
        const int idx = j*256 + tid, row = idx >> 3;
        const int colx = ((idx & 7) * 8) ^ (F_(row) * 8);
        gload_lds16(Kbase + (size_t)row * DH_ + colx, &Kl[(j*256 + w*64) * 8]);
    }
    auto stageQ = [&](int qt, int buf) {
        for (int j = 0; j < 4; ++j) {
            const int idx = j*256 + tid, row = idx >> 3;
            const int colx = ((idx & 7) * 8) ^ (F_(row) * 8);
            gload_lds16(Qbase + (size_t)(qt*128 + row) * DH_ + colx,
                        &Ql[buf][(j*256 + w*64) * 8]);
        }
    };
    stageQ(0, 0);
    __syncthreads();

    bf16x8 bk[2][2];
    for (int ks = 0; ks < 2; ++ks) {
        const int bc = ks * 64 + 16 * (lane >> 4);
        bk[ks][0] = *(const bf16x8*)lds_swz(Kl, w*32 + (lane&15), bc);
        bk[ks][1] = *(const bf16x8*)lds_swz(Kl, w*32 + 16 + (lane&15), bc);
    }

    float lsum0 = 0.f, lsum1 = 0.f;
    int cur = 0;
    for (int qt = 0; qt < S_/128; ++qt) {
        if (qt + 1 < S_/128) stageQ(qt + 1, cur ^ 1);
        #pragma unroll
        for (int qi = 0; qi < 8; ++qi) {
            f32x4 s0 = {}, s1 = {};
            for (int ks = 0; ks < 2; ++ks) {
                const int bc = ks * 64 + 16 * (lane >> 4);
                bf16x8 aq = *(const bf16x8*)lds_swz(&Ql[cur][0], qi*16 + (lane&15), bc);
                s0 = MFMA16(aq, bk[ks][0], s0);
                s1 = MFMA16(aq, bk[ks][1], s1);
            }
            for (int r = 0; r < 4; ++r) {
                lsum0 += exp2_hw(s0[r]);
                lsum1 += exp2_hw(s1[r]);
            }
        }
        cur ^= 1;
        if (qt + 1 < S_/128) __syncthreads();
    }
    lsum0 += __shfl_xor(lsum0, 16); lsum0 += __shfl_xor(lsum0, 32);
    lsum1 += __shfl_xor(lsum1, 16); lsum1 += __shfl_xor(lsum1, 32);
    if (lane < 16) {
        rlbuf[w*32 + lane]      = 1.0f / lsum0;
        rlbuf[w*32 + 16 + lane] = 1.0f / lsum1;
    }
    __syncthreads();

    bf16* Vb = Vt + (size_t)bh * DH_ * S_ + k0;
    const int d = tid >> 2, kk = (tid & 3) * 32;
    for (int c = 0; c < 4; ++c) {
        bf16x8* p = reinterpret_cast<bf16x8*>(Vb + (size_t)d * S_ + kk + c*8);
        bf16x8 v = *p, o;
        for (int jj = 0; jj < 8; ++jj)
            o[jj] = (bf16)((float)v[jj] * rlbuf[kk + c*8 + jj]);
        *p = o;
    }
}

// ---------------- pass 2: O = exp2(S') @ V'; 128q blocks, 32 q/wave ----------
__global__ __launch_bounds__(256) void k_attn(
    const bf16* __restrict__ Qb, const bf16* __restrict__ Kb,
    const bf16* __restrict__ Vt, bf16* __restrict__ AO)
{
    // [0,16384) Ql (128 rows x 128B) -> per-wave Pl after hoist
    // [16384,32768) Kl dbuf; [32768,49152) Vl dbuf
    __shared__ __align__(16) char smem[49152];
    const int tid = threadIdx.x, lane = tid & 63, w = tid >> 6;
    const int g = blockIdx.x, xcd = g & 7, li = g >> 3;
    const int bh = xcd * 4 + (li >> 4);
    const int q0 = (li & 15) * 128;
    const bf16* Qbase = Qb + ((size_t)bh * S_ + q0) * DH_;
    const bf16* Kbase = Kb + (size_t)bh * S_ * DH_;
    const bf16* Vbase = Vt + (size_t)bh * DH_ * S_;
    char* QP  = smem;
    char* Plw = smem + w * 4096;   // wave w's 32 Q rows == its Pl region

    // stage Q (128 rows x 64 dh)
    for (int j = 0; j < 4; ++j) {
        const int idx = j*256 + tid, row = idx >> 3;
        const int colx = ((idx & 7) * 8) ^ (F_(row) * 8);
        gload_lds16(Qbase + (size_t)row * DH_ + colx, QP + (j*256 + w*64) * 16);
    }
    auto stageKV = [&](int kt, int buf) {
        for (int j = 0; j < 2; ++j) {
            const int idx = j*256 + tid, row = idx >> 3;
            const int colx = ((idx & 7) * 8) ^ (F_(row) * 8);
            gload_lds16(Kbase + (size_t)(kt*64 + row) * DH_ + colx,
                        smem + 16384 + buf*8192 + (j*256 + w*64) * 16);
            gload_lds16(Vbase + (size_t)row * S_ + kt*64 + colx,
                        smem + 32768 + buf*8192 + (j*256 + w*64) * 16);
        }
    };
    stageKV(0, 0);
    __syncthreads();

    // hoist Q fragments: bq[qi][ks] -> 16 VGPRs (wave-private rows)
    bf16x8 bq[2][2];
    for (int qi = 0; qi < 2; ++qi)
        for (int ks = 0; ks < 2; ++ks)
            bq[qi][ks] = *(const bf16x8*)lds_swz(QP, w*32 + qi*16 + (lane&15),
                                                 ks*64 + 16*(lane>>4));

    f32x4 oacc[4][2] = {};
    int cur = 0;
    for (int kt = 0; kt < S_/64; ++kt) {
        if (kt + 1 < S_/64) stageKV(kt + 1, cur ^ 1);
        char* Kc = smem + 16384 + cur*8192;
        char* Vc = smem + 32768 + cur*8192;

        // swapped QK^T, kf-sliced; P = exp2(s') -> Plw [32q][64k]
        for (int kf = 0; kf < 4; ++kf) {
            f32x4 sacc[2] = {};
            for (int ks = 0; ks < 2; ++ks) {
                bf16x8 ak = *(const bf16x8*)lds_swz(Kc, kf*16 + (lane&15),
                                                    ks*64 + 16*(lane>>4));
                for (int qi = 0; qi < 2; ++qi)
                    sacc[qi] = MFMA16(ak, bq[qi][ks], sacc[qi]);
            }
            for (int qi = 0; qi < 2; ++qi) {
                uint2 pw;
                pw.x = cvt_pk_bf16(exp2_hw(sacc[qi][0]), exp2_hw(sacc[qi][1]));
                pw.y = cvt_pk_bf16(exp2_hw(sacc[qi][2]), exp2_hw(sacc[qi][3]));
                *(uint2*)lds_swz(Plw, qi*16 + (lane&15), kf*32 + (lane>>4)*8) = pw;
            }
        }

        // PV: O^T[64d][32q] += V'-tile @ P^T (4x2 register blocking)
        for (int ks = 0; ks < 2; ++ks) {
            const int bc = ks*64 + 16*(lane>>4);
            bf16x8 av[4], bp[2];
            for (int df = 0; df < 4; ++df)
                av[df] = *(const bf16x8*)lds_swz(Vc, df*16 + (lane&15), bc);
            for (int qi = 0; qi < 2; ++qi)
                bp[qi] = *(const bf16x8*)lds_swz(Plw, qi*16 + (lane&15), bc);
            for (int df = 0; df < 4; ++df)
                for (int qi = 0; qi < 2; ++qi)
                    oacc[df][qi] = MFMA16(av[df], bp[qi], oacc[df][qi]);
        }
        cur ^= 1;
        if (kt + 1 < S_/64) __syncthreads();
    }

    // epilogue: AO[b, q, h*64+d], 4 consecutive d -> 8B stores
    const int b = bh >> 4, h = bh & 15;
    for (int df = 0; df < 4; ++df)
        for (int qi = 0; qi < 2; ++qi) {
            const int d0 = df*16 + (lane >> 4) * 4;
            const int q = q0 + w*32 + qi*16 + (lane & 15);
            bf16x4 o;
            for (int r = 0; r < 4; ++r) o[r] = (bf16)oacc[df][qi][r];
            *reinterpret_cast<bf16x4*>(
                AO + ((size_t)(b*S_ + q))*E_ + h*DH_ + d0) = o;
        }
}

extern "C" void kernel_launch(void* const* d_in, const int* in_sizes, int n_in,
                              void* d_out, int out_size, void* d_ws, size_t ws_size,
                              hipStream_t stream) {
    const float* input = (const float*)d_in[0];
    const float* Wqkv  = (const float*)d_in[1];
    const float* bqkv  = (const float*)d_in[2];
    const float* Wo    = (const float*)d_in[3];
    const float* bo    = (const float*)d_in[4];
    float* out = (float*)d_out;

    char* ws = (char*)d_ws;
    bf16*  Xb   = (bf16*) (ws + 0);
    bf16*  Wqb  = (bf16*) (ws + 8388608);
    bf16*  Wob  = (bf16*) (ws + 14680064);
    bf16*  Qb   = (bf16*) (ws + 16777216);
    bf16*  Kb   = (bf16*) (ws + 25165824);
    bf16*  Vtg  = (bf16*) (ws + 33554432);
    bf16*  AO   = (bf16*) (ws + 41943040);

    k_f2b3<<<(NX_ + NW_ + NWO_) / 1024, 256, 0, stream>>>(
        input, Wqkv, Wo, Xb, Wqb, Wob);

    k_gemm<0><<<768, 256, 0, stream>>>(Xb, Wqb, bqkv, Qb, Kb, Vtg, nullptr);

    k_colsum<<<512, 256, 0, stream>>>(Qb, Kb, Vtg);

    k_attn<<<512, 256, 0, stream>>>(Qb, Kb, Vtg, AO);

    k_gemm<1><<<256, 256, 0, stream>>>(AO, Wob, bo, nullptr, nullptr, nullptr, out);
}